// Round 2
// baseline (4777.341 us; speedup 1.0000x reference)
//
#include <hip/hip_runtime.h>
#include <math.h>

// SpatialGRU on MFMA. B=64, C=16, L=64, R=64, U=64, D=208 (pad K to 224).
// One launch per anti-diagonal (127). One block (512 thr / 8 waves) per cell.
// Phase A: C1[64 b][448 kp] = hq[64][224] @ W^T  (28 N-tiles, 7 K-steps, bf16 MFMA)
// Phase B: C2[64 b][64 u]   = P[64][224] @ U2^T  (P = rr.*hu overwrites hq in LDS)
// State ring stays fp32; bf16 only on matmul inputs.

typedef short s16x8 __attribute__((ext_vector_type(8)));
typedef float f32x4 __attribute__((ext_vector_type(4)));

#define ASTR 232                 // hq/P row stride in bf16 elems (464B: conflict-spread, 16B-aligned)
#define RINGSZ (64*4096)         // one diagonal slot: [r][b][u] fp32

// ws layout: WF bf16[28*7*512] | UF bf16[4*7*512] | XT bf16[4096*1024] | BA f32[512] | RING f32[3*RINGSZ]
#define N_WF (28*7*512)
#define N_UF (4*7*512)
#define N_XT (4096*1024)

__device__ __forceinline__ unsigned short f2bf(float v) {
    unsigned int x = __float_as_uint(v);
    unsigned int r = (x + 0x7fffu + ((x >> 16) & 1u)) >> 16;
    return (unsigned short)r;
}

// ---- prep: pack weights into MFMA B-fragment lane order ----
__global__ __launch_bounds__(256) void prep_pack(
    const float* __restrict__ wr_w, const float* __restrict__ wr_b,
    const float* __restrict__ wz_w, const float* __restrict__ wz_b,
    const float* __restrict__ wij_w, const float* __restrict__ U_w,
    unsigned short* __restrict__ WF, unsigned short* __restrict__ UF,
    float* __restrict__ BAf)
{
    int idx = blockIdx.x * 256 + threadIdx.x;
    if (idx < 28*7*64) {                       // WF: frag rows (nt*7+ks, lane)
        int frag = idx >> 6, lane = idx & 63;
        int nt = frag / 7, ks = frag % 7;
        int kp = nt*16 + (lane & 15);
        int kb = ks*32 + ((lane >> 4) << 3);
        #pragma unroll
        for (int e = 0; e < 8; ++e) {
            int k = kb + e;
            float v = 0.f;
            if (k < 208) {
                if (kp < 192) v = wr_w[kp*208 + k];
                else { int q = kp - 192; v = wz_w[((q & 3)*64 + (q >> 2))*208 + k]; }
            }
            WF[idx*8 + e] = f2bf(v);
        }
        return;
    }
    idx -= 28*7*64;
    if (idx < 4*7*64) {                        // UF
        int frag = idx >> 6, lane = idx & 63;
        int t2 = frag / 7, ks = frag % 7;
        int u = t2*16 + (lane & 15);
        int kb = ks*32 + ((lane >> 4) << 3);
        #pragma unroll
        for (int e = 0; e < 8; ++e) {
            int k = kb + e;
            float v = 0.f;
            if (k < 192) v = U_w[u*192 + k];
            else if (k < 208) v = wij_w[u*16 + (k - 192)];
            UF[idx*8 + e] = f2bf(v);
        }
        return;
    }
    idx -= 4*7*64;
    if (idx < 512) {                           // BA (kp order, z gate-interleaved)
        float v = 0.f;
        if (idx < 192) v = wr_b[idx];
        else if (idx < 448) { int q = idx - 192; v = wz_b[(q & 3)*64 + (q >> 2)]; }
        BAf[idx] = v;
    }
}

// ---- prep: transpose inputs (B,C,L,R) -> XT[(l,r)][(b,c)] bf16 ----
__global__ __launch_bounds__(256) void xpose(const float* __restrict__ inp,
                                             unsigned short* __restrict__ XT)
{
    __shared__ float tile[32][33];
    int bi = blockIdx.x;   // lr / 32   (128)
    int bj = blockIdx.y;   // bc / 32   (32)
    int tx = threadIdx.x & 31, ty = threadIdx.x >> 5;  // ty 0..7
    #pragma unroll
    for (int yy = 0; yy < 4; ++yy) {
        int bc = bj*32 + ty*4 + yy;
        tile[ty*4 + yy][tx] = inp[bc*4096 + bi*32 + tx];
    }
    __syncthreads();
    #pragma unroll
    for (int yy = 0; yy < 4; ++yy) {
        int lr = bi*32 + ty*4 + yy;
        XT[lr*1024 + bj*32 + tx] = f2bf(tile[tx][ty*4 + yy]);
    }
}

__global__ __launch_bounds__(512) void diag_step(
    int d,
    const unsigned short* __restrict__ WF,
    const unsigned short* __restrict__ UF,
    const float* __restrict__ BAf,
    const unsigned short* __restrict__ XT,
    float* __restrict__ RING,
    const float* __restrict__ wij_b,
    float* __restrict__ out)
{
    __shared__ unsigned short hq_s[64*ASTR];   // hq then P (bf16)
    __shared__ float ZH_s[64*68];
    __shared__ float ZI_s[64*68];

    const int lmin = (d > 63) ? (d - 63) : 0;
    const int l = lmin + blockIdx.x;
    const int r = d - l;

    const float* Hm1 = RING + ((d + 2) % 3) * RINGSZ;
    const float* Hm2 = RING + ((d + 1) % 3) * RINGSZ;
    float*       Hc  = RING + (d % 3) * RINGSZ;

    const int tid = threadIdx.x;

    // ---- stage hq = [ht|hl|hd|x|0] bf16; thread (b, jq) does 14 pairs ----
    {
        const int b = tid >> 3, jq = tid & 7;
        #pragma unroll
        for (int p = 0; p < 14; ++p) {
            const int j = jq*28 + 2*p;
            unsigned int packed;
            if (j < 192) {
                const float* src; bool ok;
                int jj;
                if (j < 64)       { src = Hm1 + r*4096;     ok = (l > 0);          jj = j; }
                else if (j < 128) { src = Hm1 + (r-1)*4096; ok = (r > 0);          jj = j - 64; }
                else              { src = Hm2 + (r-1)*4096; ok = (l > 0 && r > 0); jj = j - 128; }
                float v0 = 0.f, v1 = 0.f;
                if (ok) { v0 = src[b*64 + jj]; v1 = src[b*64 + jj + 1]; }
                packed = (unsigned int)f2bf(v0) | ((unsigned int)f2bf(v1) << 16);
            } else if (j < 208) {
                const unsigned short* xs = XT + (l*64 + r)*1024 + b*16 + (j - 192);
                packed = (unsigned int)xs[0] | ((unsigned int)xs[1] << 16);
            } else {
                packed = 0u;
            }
            *(unsigned int*)&hq_s[b*ASTR + j] = packed;
        }
    }
    __syncthreads();

    const int wv = tid >> 6, lane = tid & 63;
    const int col = lane & 15, rowq = (lane >> 4) << 2;

    // ---- phase A GEMM: wave (mh=wv>>2, nh=wv&3): 2 M-tiles x 7 N-tiles x 7 K ----
    const int nh = wv & 3, mh = wv >> 2;
    f32x4 acc[7][2];
    #pragma unroll
    for (int t = 0; t < 7; ++t) { acc[t][0] = (f32x4){0,0,0,0}; acc[t][1] = (f32x4){0,0,0,0}; }
    #pragma unroll
    for (int ks = 0; ks < 7; ++ks) {
        s16x8 af0 = *(const s16x8*)&hq_s[(mh*32 + col)*ASTR + ks*32 + (rowq << 1)];
        s16x8 af1 = *(const s16x8*)&hq_s[(mh*32 + 16 + col)*ASTR + ks*32 + (rowq << 1)];
        #pragma unroll
        for (int t = 0; t < 7; ++t) {
            s16x8 bf = *(const s16x8*)&WF[(((nh*7 + t)*7 + ks)*64 + lane)*8];
            acc[t][0] = __builtin_amdgcn_mfma_f32_16x16x32_bf16(af0, bf, acc[t][0], 0, 0, 0);
            acc[t][1] = __builtin_amdgcn_mfma_f32_16x16x32_bf16(af1, bf, acc[t][1], 0, 0, 0);
        }
    }
    __syncthreads();

    // ---- activations: rr -> P (overwrite hq cols 0..191); z -> softmax gates ----
    #pragma unroll
    for (int t = 0; t < 7; ++t) {
        const int kp = (nh*7 + t)*16 + col;
        const float bias = BAf[kp];
        const bool isrr = kp < 192;
        #pragma unroll
        for (int mti = 0; mti < 2; ++mti) {
            #pragma unroll
            for (int reg = 0; reg < 4; ++reg) {
                const int b = (mh*2 + mti)*16 + rowq + reg;
                const float val = acc[t][mti][reg] + bias;
                if (isrr) {
                    // P[b][kp] = sigmoid(val) * hu[kp],  hu = [hl|ht|hd] fp32 ring
                    float hu;
                    if (kp < 64)       hu = (r > 0) ? Hm1[(r-1)*4096 + b*64 + kp] : 0.f;
                    else if (kp < 128) hu = (l > 0) ? Hm1[r*4096 + b*64 + (kp-64)] : 0.f;
                    else               hu = (l > 0 && r > 0) ? Hm2[(r-1)*4096 + b*64 + (kp-128)] : 0.f;
                    const float rr = 1.f / (1.f + __expf(-val));
                    hq_s[b*ASTR + kp] = f2bf(rr * hu);
                } else {
                    // softmax over gate quad (g = lane&3: [i,l,t,d])
                    const int g = lane & 3;
                    const int u = (kp - 192) >> 2;
                    float m = fmaxf(val, __shfl_xor(val, 1, 64));
                    m = fmaxf(m, __shfl_xor(m, 2, 64));
                    float e = __expf(val - m);
                    float s = e + __shfl_xor(e, 1, 64);
                    s += __shfl_xor(s, 2, 64);
                    const float gate = e / s;
                    float hsel = 0.f;
                    if (g == 1)      hsel = (r > 0) ? Hm1[(r-1)*4096 + b*64 + u] : 0.f;
                    else if (g == 2) hsel = (l > 0) ? Hm1[r*4096 + b*64 + u] : 0.f;
                    else if (g == 3) hsel = (l > 0 && r > 0) ? Hm2[(r-1)*4096 + b*64 + u] : 0.f;
                    float tt = gate * hsel;
                    float s3 = tt + __shfl_xor(tt, 1, 64);
                    s3 += __shfl_xor(s3, 2, 64);
                    if (g == 0) { ZI_s[b*68 + u] = gate; ZH_s[b*68 + u] = s3; }
                }
            }
        }
    }
    __syncthreads();

    // ---- phase B GEMM: wave (mt=wv>>1, t2 pair=(wv&1)*2): 1 M x 2 N x 7 K ----
    {
        const int mt = wv >> 1, th = (wv & 1) * 2;
        f32x4 acc2[2];
        acc2[0] = (f32x4){0,0,0,0}; acc2[1] = (f32x4){0,0,0,0};
        #pragma unroll
        for (int ks = 0; ks < 7; ++ks) {
            s16x8 a2 = *(const s16x8*)&hq_s[(mt*16 + col)*ASTR + ks*32 + (rowq << 1)];
            #pragma unroll
            for (int i = 0; i < 2; ++i) {
                s16x8 bf = *(const s16x8*)&UF[(((th + i)*7 + ks)*64 + lane)*8];
                acc2[i] = __builtin_amdgcn_mfma_f32_16x16x32_bf16(a2, bf, acc2[i], 0, 0, 0);
            }
        }
        // epilogue
        const bool last = (d == 126);
        #pragma unroll
        for (int i = 0; i < 2; ++i) {
            const int u = (th + i)*16 + col;
            const float wb = wij_b[u];
            #pragma unroll
            for (int reg = 0; reg < 4; ++reg) {
                const int b = mt*16 + rowq + reg;
                const float hn = tanhf(acc2[i][reg] + wb);
                const float h = ZH_s[b*68 + u] + ZI_s[b*68 + u] * hn;
                Hc[r*4096 + b*64 + u] = h;
                if (last) out[b*64 + u] = h;
            }
        }
    }
}

extern "C" void kernel_launch(void* const* d_in, const int* in_sizes, int n_in,
                              void* d_out, int out_size, void* d_ws, size_t ws_size,
                              hipStream_t stream)
{
    const float* inp   = (const float*)d_in[0];
    const float* wr_w  = (const float*)d_in[1];
    const float* wr_b  = (const float*)d_in[2];
    const float* wz_w  = (const float*)d_in[3];
    const float* wz_b  = (const float*)d_in[4];
    const float* wij_w = (const float*)d_in[5];
    const float* wij_b = (const float*)d_in[6];
    const float* U_w   = (const float*)d_in[7];
    float* out = (float*)d_out;

    unsigned short* WF = (unsigned short*)d_ws;
    unsigned short* UF = WF + N_WF;
    unsigned short* XT = UF + N_UF;
    float* BAf  = (float*)(XT + N_XT);
    float* RING = BAf + 512;

    prep_pack<<<58, 256, 0, stream>>>(wr_w, wr_b, wz_w, wz_b, wij_w, U_w, WF, UF, BAf);
    xpose<<<dim3(128, 32), 256, 0, stream>>>(inp, XT);

    for (int d = 0; d < 127; ++d) {
        int lmin = (d > 63) ? (d - 63) : 0;
        int lmax = (d < 63) ? d : 63;
        diag_step<<<lmax - lmin + 1, 512, 0, stream>>>(d, WF, UF, BAf, XT, RING, wij_b, out);
    }
}